// Round 1
// baseline (95.491 us; speedup 1.0000x reference)
//
#include <hip/hip_runtime.h>

// Caps_BN: BatchNorm2d (affine=False, training stats) + grouped 1x1 conv (16 groups
// of 32x32) + bias, folded: out = (W * rstd) @ x + (bias - (W*rstd) @ mean).
//
// Shapes: x (64, 512, 32, 32) f32; weight (16, 32, 32) f32; bias (512,) f32.
// N*H*W per channel = 64*1024 = 65536.
//
// Workspace layout (floats):
//   [0, 512)          mean per channel
//   [512, 1024)       rstd per channel
//   [1024, 17408)     W' folded weight (c, o, i)
//   [17408, 17920)    b' folded bias (c, o)

#define NELEM_PER_CH 65536.0f

__global__ __launch_bounds__(256) void caps_stats(const float* __restrict__ x,
                                                  float* __restrict__ ws) {
    const int ch = blockIdx.x;      // 0..511
    const int tid = threadIdx.x;    // 0..255
    const float4* __restrict__ x4 = (const float4*)x;

    float s = 0.f, ss = 0.f;
    // channel row of image n: 1024 floats = 256 float4 at x4[(n*512 + ch)*256 + q]
#pragma unroll 4
    for (int n = 0; n < 64; ++n) {
        float4 v = x4[((size_t)n * 512 + ch) * 256 + tid];
        s  += v.x + v.y + v.z + v.w;
        ss += v.x * v.x + v.y * v.y + v.z * v.z + v.w * v.w;
    }

    // wave64 reduce
#pragma unroll
    for (int off = 32; off > 0; off >>= 1) {
        s  += __shfl_down(s, off);
        ss += __shfl_down(ss, off);
    }
    __shared__ float red[4][2];
    const int wid = tid >> 6;
    if ((tid & 63) == 0) { red[wid][0] = s; red[wid][1] = ss; }
    __syncthreads();
    if (tid == 0) {
        float S = 0.f, SS = 0.f;
#pragma unroll
        for (int w = 0; w < 4; ++w) { S += red[w][0]; SS += red[w][1]; }
        float mean = S / NELEM_PER_CH;
        float var = SS / NELEM_PER_CH - mean * mean;
        ws[ch] = mean;
        ws[512 + ch] = rsqrtf(var + 1e-5f);
    }
}

// One block per capsule c; 1024 threads, thread t = o*32 + i.
__global__ __launch_bounds__(1024) void caps_fold(const float* __restrict__ w,
                                                  const float* __restrict__ bias,
                                                  float* __restrict__ ws) {
    const int c = blockIdx.x;
    const int t = threadIdx.x;
    const int o = t >> 5;
    const int i = t & 31;

    const float mean = ws[c * 32 + i];
    const float rstd = ws[512 + c * 32 + i];
    const float wv = w[c * 1024 + t] * rstd;
    ws[1024 + c * 1024 + t] = wv;

    // reduce wv*mean over i within each aligned 32-lane half of the wave
    float prod = wv * mean;
#pragma unroll
    for (int off = 16; off > 0; off >>= 1) prod += __shfl_xor(prod, off);
    if (i == 0) ws[17408 + c * 32 + o] = bias[c * 32 + o] - prod;
}

// Main: one thread per hw column of one (n, c) tile.
// grid (4, 16, 64) = (hw/256, c, n); block 256.
__global__ __launch_bounds__(256) void caps_main(const float* __restrict__ x,
                                                 const float* __restrict__ ws,
                                                 float* __restrict__ out) {
    const int hw = blockIdx.x * 256 + threadIdx.x;  // 0..1023
    const int c = blockIdx.y;
    const int n = blockIdx.z;

    const size_t base = (((size_t)n * 16 + c) * 32) * 1024 + hw;
    const float* __restrict__ Wc = ws + 1024 + c * 1024;   // W'[c][o][i]
    const float* __restrict__ b2 = ws + 17408 + c * 32;    // b'[c][o]

    float xv[32];
#pragma unroll
    for (int i = 0; i < 32; ++i) xv[i] = x[base + (size_t)i * 1024];

#pragma unroll 4
    for (int o = 0; o < 32; ++o) {
        float acc = b2[o];                    // uniform scalar load
#pragma unroll
        for (int i = 0; i < 32; ++i)
            acc += Wc[o * 32 + i] * xv[i];    // uniform W' -> s_load; v_fmac v,s,v
        out[base + (size_t)o * 1024] = acc;
    }
}

extern "C" void kernel_launch(void* const* d_in, const int* in_sizes, int n_in,
                              void* d_out, int out_size, void* d_ws, size_t ws_size,
                              hipStream_t stream) {
    const float* x    = (const float*)d_in[0];
    const float* w    = (const float*)d_in[1];
    const float* bias = (const float*)d_in[2];
    float* out = (float*)d_out;
    float* ws  = (float*)d_ws;

    caps_stats<<<512, 256, 0, stream>>>(x, ws);
    caps_fold<<<16, 1024, 0, stream>>>(w, bias, ws);
    caps_main<<<dim3(4, 16, 64), 256, 0, stream>>>(x, ws, out);
}